// Round 1
// baseline (470.942 us; speedup 1.0000x reference)
//
#include <hip/hip_runtime.h>

// Problem constants (from setup_inputs): B=16, C_img=3, H=448, W=1024.
#define BB 16
#define HH 448
#define WW 1024
constexpr int HW    = HH * WW;            // 458752
constexpr int ROWS  = 4;                  // rows per block
constexpr int RGRP  = HH / ROWS;          // 112 row-groups per image
constexpr int NBLK  = BB * RGRP;          // 1792 blocks, one per (b, row-group)
constexpr int NTHR  = 256;                // 256 thr x 4 px = one full row
constexpr long long TOTAL = (long long)BB * HW;

// Block layout: thread t owns pixels [4t, 4t+3] of each row in its group.
// Flow for row y+1 is loaded while row y is processed, then rotated into
// the "current" registers -> each flow row is loaded/exp'd ~1.25x total
// (vs 3x in the previous grid-stride version). Right-neighbor flow comes
// from the next lane via shuffle (lane-63 reloads 2 scalars as fallback).

__global__ __launch_bounds__(NTHR) void elbo_main(
    const float* __restrict__ mean, const float* __restrict__ lvar,
    const float* __restrict__ img1, const float* __restrict__ img2,
    const float* __restrict__ target, const float* __restrict__ eps,
    float2* __restrict__ partials)
{
    // XCD-chunked bijective swizzle (NBLK % 8 == 0): each XCD gets a
    // contiguous band of rows -> img2 gather rows stay resident in its L2.
    constexpr int NXCD = 8, CPX = NBLK / NXCD;
    const int wg = (blockIdx.x % NXCD) * CPX + blockIdx.x / NXCD;

    const int b  = wg / RGRP;
    const int y0 = (wg - b * RGRP) * ROWS;
    const int t  = threadIdx.x;
    const int x  = t << 2;                  // base x of this thread's float4

    const int fbase = b * 2 * HW;           // (B,2,H,W) channel-0 base
    const int ibase = b * 3 * HW;           // (B,3,H,W) channel-0 base

    float se = 0.f;   // elbo partial (data + smooth - 0.5*sum(logvar))
    float sp = 0.f;   // epe partial

    float u[4], v[4], un[4], vn[4];

    // Load flow row y (float4, fully coalesced). When 'contrib' is set this
    // row belongs to this block, so fuse in the EPE and logvar terms here
    // (mean/lvar are live in registers -> no second pass over them).
    auto load_flow = [&](int y, float* uu, float* vv, bool contrib) {
        const int o = fbase + y * WW + x;
        const float4 m0 = *(const float4*)(mean + o);
        const float4 m1 = *(const float4*)(mean + o + HW);
        const float4 l0 = *(const float4*)(lvar + o);
        const float4 l1 = *(const float4*)(lvar + o + HW);
        const float4 e0 = *(const float4*)(eps  + o);
        const float4 e1 = *(const float4*)(eps  + o + HW);
        uu[0] = m0.x + __expf(0.5f * l0.x) * e0.x;
        uu[1] = m0.y + __expf(0.5f * l0.y) * e0.y;
        uu[2] = m0.z + __expf(0.5f * l0.z) * e0.z;
        uu[3] = m0.w + __expf(0.5f * l0.w) * e0.w;
        vv[0] = m1.x + __expf(0.5f * l1.x) * e1.x;
        vv[1] = m1.y + __expf(0.5f * l1.y) * e1.y;
        vv[2] = m1.z + __expf(0.5f * l1.z) * e1.z;
        vv[3] = m1.w + __expf(0.5f * l1.w) * e1.w;
        if (contrib) {
            const float4 t0 = *(const float4*)(target + o);
            const float4 t1 = *(const float4*)(target + o + HW);
            float du, dv;
            du = m0.x - t0.x; dv = m1.x - t1.x; sp += sqrtf(du*du + dv*dv);
            du = m0.y - t0.y; dv = m1.y - t1.y; sp += sqrtf(du*du + dv*dv);
            du = m0.z - t0.z; dv = m1.z - t1.z; sp += sqrtf(du*du + dv*dv);
            du = m0.w - t0.w; dv = m1.w - t1.w; sp += sqrtf(du*du + dv*dv);
            se -= 0.5f * (l0.x + l0.y + l0.z + l0.w +
                          l1.x + l1.y + l1.z + l1.w);
        }
    };

    load_flow(y0, u, v, true);

    for (int r = 0; r < ROWS; ++r) {
        const int y = y0 + r;
        const bool have_dn = (y + 1) < HH;   // false only for image row 447
        if (have_dn) load_flow(y + 1, un, vn, r < ROWS - 1);

        // right-neighbor flow at x+4 = next lane's pixel 0
        float uR = __shfl_down(u[0], 1);
        float vR = __shfl_down(v[0], 1);
        if (((t & 63) == 63) && (t != NTHR - 1)) {   // wave boundary fallback
            const int o = fbase + y * WW + x + 4;
            uR = mean[o]      + __expf(0.5f * lvar[o])      * eps[o];
            vR = mean[o + HW] + __expf(0.5f * lvar[o + HW]) * eps[o + HW];
        }

        const int ro = y * WW + x;
        const float4 g0 = *(const float4*)(img1 + ibase + ro);
        const float4 g1 = *(const float4*)(img1 + ibase + HW + ro);
        const float4 g2 = *(const float4*)(img1 + ibase + 2 * HW + ro);
        const float i1c0[4] = {g0.x, g0.y, g0.z, g0.w};
        const float i1c1[4] = {g1.x, g1.y, g1.z, g1.w};
        const float i1c2[4] = {g2.x, g2.y, g2.z, g2.w};

        const float* __restrict__ p2 = img2 + ibase;

        #pragma unroll
        for (int i = 0; i < 4; ++i) {
            const float ui = u[i], vi = v[i];
            const int gx = x + i;

            // ---- smoothness ----
            float dx2 = 0.f, dy2 = 0.f;
            if (gx < WW - 1) {
                const float ur = (i < 3) ? u[i + 1] : uR;
                const float vr = (i < 3) ? v[i + 1] : vR;
                const float a = ur - ui, c = vr - vi;
                dx2 = a * a + c * c;
            }
            if (have_dn) {
                const float a = un[i] - ui, c = vn[i] - vi;
                dy2 = a * a + c * c;
            }
            se += sqrtf(dx2 + dy2 + 1e-5f);

            // ---- data term: bilinear warp of img2 ----
            const float xs = (float)gx + ui;
            const float ys = (float)y  + vi;
            const float x0f = floorf(xs), y0f = floorf(ys);
            const float wx = xs - x0f,    wy = ys - y0f;
            int x0 = (int)x0f; x0 = min(max(x0, 0), WW - 1);
            const int x1 = min(x0 + 1, WW - 1);
            int yy0 = (int)y0f; yy0 = min(max(yy0, 0), HH - 1);
            const int yy1 = min(yy0 + 1, HH - 1);
            const int i00 = yy0 * WW + x0, i01 = yy0 * WW + x1;
            const int i10 = yy1 * WW + x0, i11 = yy1 * WW + x1;

            float A = 0.f;
            {
                const float v00 = p2[i00], v01 = p2[i01];
                const float v10 = p2[i10], v11 = p2[i11];
                const float top = v00 + wx * (v01 - v00);
                const float bot = v10 + wx * (v11 - v10);
                const float w   = top + wy * (bot - top);
                const float d   = i1c0[i] - w;
                A += d * d;
            }
            {
                const float v00 = p2[HW + i00], v01 = p2[HW + i01];
                const float v10 = p2[HW + i10], v11 = p2[HW + i11];
                const float top = v00 + wx * (v01 - v00);
                const float bot = v10 + wx * (v11 - v10);
                const float w   = top + wy * (bot - top);
                const float d   = i1c1[i] - w;
                A += d * d;
            }
            {
                const float v00 = p2[2*HW + i00], v01 = p2[2*HW + i01];
                const float v10 = p2[2*HW + i10], v11 = p2[2*HW + i11];
                const float top = v00 + wx * (v01 - v00);
                const float bot = v10 + wx * (v11 - v10);
                const float w   = top + wy * (bot - top);
                const float d   = i1c2[i] - w;
                A += d * d;
            }
            se += sqrtf(A + 1e-5f);
        }

        if (r < ROWS - 1) {
            #pragma unroll
            for (int i = 0; i < 4; ++i) { u[i] = un[i]; v[i] = vn[i]; }
        }
    }

    // ---- block reduction: wave shuffle then LDS across 4 waves ----
    #pragma unroll
    for (int off = 32; off > 0; off >>= 1) {
        se += __shfl_down(se, off);
        sp += __shfl_down(sp, off);
    }
    __shared__ float s_e[NTHR / 64], s_p[NTHR / 64];
    const int lane = threadIdx.x & 63;
    const int wid  = threadIdx.x >> 6;
    if (lane == 0) { s_e[wid] = se; s_p[wid] = sp; }
    __syncthreads();
    if (threadIdx.x == 0) {
        float te = 0.0f, tp = 0.0f;
        #pragma unroll
        for (int i = 0; i < NTHR / 64; ++i) { te += s_e[i]; tp += s_p[i]; }
        partials[blockIdx.x] = make_float2(te, tp);
    }
}

__global__ __launch_bounds__(256) void elbo_final(
    const float2* __restrict__ partials, float* __restrict__ out)
{
    double se = 0.0, sp = 0.0;
    for (int i = threadIdx.x; i < NBLK; i += 256) {
        const float2 v = partials[i];
        se += (double)v.x;
        sp += (double)v.y;
    }
    #pragma unroll
    for (int off = 32; off > 0; off >>= 1) {
        se += __shfl_down(se, off);
        sp += __shfl_down(sp, off);
    }
    __shared__ double s_e[4], s_p[4];
    const int lane = threadIdx.x & 63;
    const int wid  = threadIdx.x >> 6;
    if (lane == 0) { s_e[wid] = se; s_p[wid] = sp; }
    __syncthreads();
    if (threadIdx.x == 0) {
        double te = 0.0, tp = 0.0;
        #pragma unroll
        for (int i = 0; i < 4; ++i) { te += s_e[i]; tp += s_p[i]; }
        out[0] = (float)(te / (double)BB);
        out[1] = (float)(tp / (double)TOTAL);
    }
}

extern "C" void kernel_launch(void* const* d_in, const int* in_sizes, int n_in,
                              void* d_out, int out_size, void* d_ws, size_t ws_size,
                              hipStream_t stream) {
    const float* mean   = (const float*)d_in[0];
    const float* logvar = (const float*)d_in[1];
    const float* img1   = (const float*)d_in[2];
    const float* img2   = (const float*)d_in[3];
    const float* target = (const float*)d_in[4];
    const float* eps    = (const float*)d_in[5];
    float* out = (float*)d_out;
    float2* partials = (float2*)d_ws;   // NBLK * 8 bytes = 14 KiB

    elbo_main<<<NBLK, NTHR, 0, stream>>>(mean, logvar, img1, img2, target, eps, partials);
    elbo_final<<<1, 256, 0, stream>>>(partials, out);
}